// Round 7
// baseline (250.270 us; speedup 1.0000x reference)
//
#include <hip/hip_runtime.h>
#include <hip/hip_bf16.h>
#include <math.h>

#define EMBED 1024
#define HEADS 16
#define DH    64
#define BATCH 2
#define SEQ   2048

typedef __attribute__((ext_vector_type(8))) short bf16x8;
typedef __attribute__((ext_vector_type(4))) short bf16x4;
typedef __attribute__((ext_vector_type(4))) float f32x4;
typedef unsigned long long u64;

#define QSCALE 0.1803368801111244f   // 0.125 * log2(e): exp(s/8) == exp2(s*QSCALE)

static __device__ __forceinline__ unsigned short f2bf(float x) {
    unsigned u = __builtin_bit_cast(unsigned, x);
    return (unsigned short)((u + 0x7fffu + ((u >> 16) & 1u)) >> 16);
}
static __device__ __forceinline__ unsigned pk2bf(float a, float b) {
    union { __hip_bfloat162 h2; unsigned u; } c;
    c.h2 = __float22bfloat162_rn(make_float2(a, b));
    return c.u;
}
// async global->LDS DMA, 16 B per lane; LDS dest = wave-uniform base + lane*16
static __device__ __forceinline__ void gl_lds16(const void* g, void* l) {
    __builtin_amdgcn_global_load_lds(
        (const __attribute__((address_space(1))) void*)g,
        (__attribute__((address_space(3))) void*)l, 16, 0, 0);
}
// convert 16 consecutive fp32 (two float4 pairs) to one bf16x8 fragment
static __device__ __forceinline__ bf16x8 cvt8(const float* p) {
    float4 a = ((const float4*)p)[0];
    float4 b = ((const float4*)p)[1];
    union { unsigned u[4]; bf16x8 v; } c;
    c.u[0] = pk2bf(a.x, a.y); c.u[1] = pk2bf(a.z, a.w);
    c.u[2] = pk2bf(b.x, b.y); c.u[3] = pk2bf(b.z, b.w);
    return c.v;
}

// ---------------------------------------------------------------------------
// Kernel 1 (R7 mega-proj): grid = (1024, 4), block = 256.
//   which 0: Q projection, C = X·W^T, out [B,H,S,DH] (R4 hybrid).
//   which 1: K projection, C = X·W^T, out [B,H,S,DH] (standard layout — K
//            returns to the verified conflict-free DMA+LDS attn path).
//   which 2: V projection TRANSPOSED, C = W·X^T, out in PV-FRAGMENT-MAJOR
//            layout Vp[bh][kt][(st*4+dt)*64 + lane][4]: attn reads each PV
//            B-fragment as one fully-coalesced 512B wave load from L2.
//   which 3: blk<512 maskpack | blk>=512 Wo fp32->bf16.
// ---------------------------------------------------------------------------
__global__ __launch_bounds__(256) void proj_mfma(
    const float* __restrict__ q, const float* __restrict__ k, const float* __restrict__ v,
    const float* __restrict__ Wq, const float* __restrict__ bq,
    const float* __restrict__ Wk, const float* __restrict__ bk,
    const float* __restrict__ Wv, const float* __restrict__ bv,
    unsigned short* __restrict__ qh, unsigned short* __restrict__ kh,
    unsigned short* __restrict__ Vp,
    const int* __restrict__ mask, u64* __restrict__ bits,
    const float* __restrict__ Wo, unsigned short* __restrict__ Wob)
{
    const int blk   = blockIdx.x;
    const int which = blockIdx.y;
    const int t     = threadIdx.x;

    if (which == 3) {                     // ---- prep jobs (no LDS, no barrier) ----
        if (blk < 512) {                  // mask -> bitmask
            const int idx = blk * 256 + t;
            const int4* src = (const int4*)(mask + (size_t)idx * 64);
            u64 wb = 0;
#pragma unroll
            for (int u = 0; u < 16; ++u) {
                int4 m = src[u];
                u64 nib = (m.x != 0 ? 1ull : 0) | (m.y != 0 ? 2ull : 0) |
                          (m.z != 0 ? 4ull : 0) | (m.w != 0 ? 8ull : 0);
                wb |= nib << (u * 4);
            }
            bits[idx] = wb;
        } else {                          // Wo fp32 -> bf16
            const int i = ((blk - 512) * 256 + t) * 8;
            float4 a = ((const float4*)(Wo + i))[0];
            float4 b = ((const float4*)(Wo + i))[1];
            unsigned o32[4] = {pk2bf(a.x, a.y), pk2bf(a.z, a.w),
                               pk2bf(b.x, b.y), pk2bf(b.z, b.w)};
            *(uint4*)(Wob + i) = *(uint4*)o32;
        }
        return;
    }

    const float* x; const float* W; const float* bias;
    if (which == 0)      { x = q; W = Wq; bias = bq; }
    else if (which == 1) { x = k; W = Wk; bias = bk; }
    else                 { x = v; W = Wv; bias = bv; }

    __shared__ unsigned short Ws[64 * 72];

    const int w    = t >> 6;
    const int lane = t & 63;
    const int l15  = lane & 15;
    const int quad = lane >> 4;

    // ---- stage W into LDS (cooperative, one pass; verified R2 layout) ----
    const int sr = t >> 2, sp = t & 3;
    {
        const float* wsrc = W + (size_t)sr * 64 + sp * 16;
        unsigned o32[8];
#pragma unroll
        for (int u4 = 0; u4 < 4; ++u4) {
            float4 a = ((const float4*)wsrc)[u4];
            o32[u4 * 2 + 0] = pk2bf(a.x, a.y);
            o32[u4 * 2 + 1] = pk2bf(a.z, a.w);
        }
        *(uint4*)&Ws[sr * 72 + sp * 16]     = *(uint4*)&o32[0];
        *(uint4*)&Ws[sr * 72 + sp * 16 + 8] = *(uint4*)&o32[4];
    }

    if (which == 2) {                     // ---- V: C = W·X^T -> fragment-major Vp ----
        const int bh = blk >> 5;          // (b,h) 0..31
        const int kt = blk & 31;          // 64-s tile = attn K-tile index
        const int b  = bh >> 4, h = bh & 15;
        const int s  = kt * 64 + w * 16 + l15;

        const float* xrow = x + ((size_t)(b * SEQ + s)) * EMBED + h * DH;
        const bf16x8 bx0 = cvt8(xrow + quad * 8);
        const bf16x8 bx1 = cvt8(xrow + 32 + quad * 8);

        __syncthreads();

        unsigned short* vtile = Vp + ((size_t)bh * 32 + kt) * 4096;
        const int qr = l15 >> 2, j = l15 & 3;
#pragma unroll
        for (int nt = 0; nt < 4; ++nt) {
            bf16x8 aw0 = *(const bf16x8*)&Ws[(nt * 16 + l15) * 72 + quad * 8];
            bf16x8 aw1 = *(const bf16x8*)&Ws[(nt * 16 + l15) * 72 + 32 + quad * 8];
            f32x4 a = {0, 0, 0, 0};
            a = __builtin_amdgcn_mfma_f32_16x16x32_bf16(aw0, bx0, a, 0, 0, 0);
            a = __builtin_amdgcn_mfma_f32_16x16x32_bf16(aw1, bx1, a, 0, 0, 0);
            // value (d = nt*16+quad*4+r, s) -> Vp frag addr:
            //   ((w*4+nt)*64 + qr*16 + quad*4 + r)*4 + j
#pragma unroll
            for (int r = 0; r < 4; ++r) {
                const int d = nt * 16 + quad * 4 + r;
                vtile[((w * 4 + nt) * 64 + qr * 16 + quad * 4 + r) * 4 + j] =
                    f2bf(a[r] + bias[d]);
            }
        }
        return;
    }

    // ---- Q/K: C = X·W^T (R4 hybrid path) ----
    const float oscale = (which == 0) ? QSCALE : 1.0f;
    unsigned short* out = (which == 0) ? qh : kh;

    const float* xrow = x + ((size_t)blk * 64 + w * 16 + l15) * 64;
    const bf16x8 af0 = cvt8(xrow + quad * 8);
    const bf16x8 af1 = cvt8(xrow + 32 + quad * 8);

    __syncthreads();

    f32x4 acc[4];
#pragma unroll
    for (int nt = 0; nt < 4; ++nt) {
        bf16x8 bf0 = *(const bf16x8*)&Ws[(nt * 16 + l15) * 72 + quad * 8];
        bf16x8 bf1 = *(const bf16x8*)&Ws[(nt * 16 + l15) * 72 + 32 + quad * 8];
        f32x4 a = {0, 0, 0, 0};
        a = __builtin_amdgcn_mfma_f32_16x16x32_bf16(af0, bf0, a, 0, 0, 0);
        a = __builtin_amdgcn_mfma_f32_16x16x32_bf16(af1, bf1, a, 0, 0, 0);
        acc[nt] = a;
    }

    const int bsidx = blk * 4 + w;
    const int b = bsidx >> 11, s = bsidx & 2047;
#pragma unroll
    for (int nt = 0; nt < 4; ++nt) {
        const int d = nt * 16 + l15;
        const float bb = bias[d];
#pragma unroll
        for (int r = 0; r < 4; ++r) {
            const int h = quad * 4 + r;
            out[(((size_t)b * HEADS + h) * SEQ + s) * DH + d] =
                f2bf((acc[nt][r] + bb) * oscale);
        }
    }
}

// ---------------------------------------------------------------------------
// Kernel 2 (R7): MFMA flash attention.
// K: DMA + double-buffered LDS + XOR b128 reads (R2 path — measured
// conflict-free: R6 removed it and SQ_LDS_BANK_CONFLICT didn't move).
// V: NO LDS — PV B-fragments read directly from L2 in fragment-major Vp
// (one 512B coalesced wave load each), issued at iteration top so the
// QK+softmax phase hides the L2 latency. This deletes the ds_read_b64
// V path that owned ALL 8.39M conflict cycles (R6 attribution).
// LDS = 2 x 8KB (K only). grid = flat 1024; bh = bid & 31.
// ---------------------------------------------------------------------------
__global__ __launch_bounds__(256, 4) void attn_kernel(
    const unsigned short* __restrict__ qh, const unsigned short* __restrict__ kh,
    const unsigned short* __restrict__ Vp, const u64* __restrict__ mbits,
    unsigned short* __restrict__ ctx)
{
    const int bid = blockIdx.x;
    const int bh  = bid & 31;
    const int q0  = (bid >> 5) * 64;
    const int b   = bh >> 4;

    __shared__ unsigned char smem[16384];   // K only: buf(8K) x2

    const int t    = threadIdx.x;
    const int w    = t >> 6;              // wave id: q-subtile (16 rows)
    const int lane = t & 63;
    const int l15  = lane & 15;
    const int quad = lane >> 4;

    const int srow   = lane >> 3;
    const int schunk = (lane & 7) ^ srow;

    const unsigned short* qb = qh + ((size_t)bh * SEQ + q0 + w * 16 + l15) * DH + quad * 8;
    const bf16x8 qf0 = *(const bf16x8*)qb;
    const bf16x8 qf1 = *(const bf16x8*)(qb + 32);

    f32x4 O[4];
#pragma unroll
    for (int dt = 0; dt < 4; ++dt) O[dt] = f32x4{0, 0, 0, 0};
    f32x4 Osum = {0, 0, 0, 0};
    const bf16x4 ones = {(short)0x3F80, (short)0x3F80, (short)0x3F80, (short)0x3F80};

    const unsigned short* kbase = kh + (size_t)bh * SEQ * DH
                                  + (size_t)srow * DH + schunk * 8;
    // V fragment base: lane's 8B slot within each (st,dt) 512B fragment row
    const unsigned short* vfrag = Vp + (size_t)bh * 32 * 4096 + lane * 4;
    const u64* mrow = mbits + ((size_t)b * SEQ + q0 + w * 16 + l15) * (SEQ / 64);

    // issue K-DMA for tile 0 into buf 0 (8 x 1KB spread over 4 waves)
    {
        unsigned char* Kd = smem;
#pragma unroll
        for (int j = 0; j < 2; ++j) {
            const int i = w * 2 + j;
            gl_lds16(kbase + (size_t)i * 8 * DH, Kd + i * 1024);
        }
    }
    u64 pm = mrow[0];
    __syncthreads();                      // drains DMA(0)

    for (int kt = 0; kt < 32; ++kt) {
        // ---- issue K-DMA for tile kt+1 into the other buffer ----
        if (kt < 31) {
            unsigned char* Kd = smem + ((kt + 1) & 1) * 8192;
            const unsigned short* g0 = kbase + (size_t)(kt + 1) * 64 * DH;
#pragma unroll
            for (int j = 0; j < 2; ++j) {
                const int i = w * 2 + j;
                gl_lds16(g0 + (size_t)i * 8 * DH, Kd + i * 1024);
            }
        }
        // ---- issue V fragment loads for THIS tile (L2; hidden under QK) ----
        const unsigned short* vt0 = vfrag + (size_t)kt * 4096;
        bf16x4 vb[4][4];
#pragma unroll
        for (int st = 0; st < 4; ++st)
#pragma unroll
            for (int dt = 0; dt < 4; ++dt)
                vb[dt][st] = *(const bf16x4*)&vt0[(st * 4 + dt) * 256];

        const u64 mb = pm;
        if (kt < 31) pm = mrow[kt + 1];

        const unsigned short* KtH = (const unsigned short*)(smem + (kt & 1) * 8192);

        // ---- S^T tile + masked exp2; P stays in registers ----
        const u64 mq = mb >> (quad * 4);
        bf16x4 p[4];
        const int rx = l15 & 7;
#pragma unroll
        for (int st = 0; st < 4; ++st) {
            const int r = st * 16 + l15;
            bf16x8 kf0 = *(const bf16x8*)&KtH[r * 64 + ((quad ^ rx)) * 8];
            bf16x8 kf1 = *(const bf16x8*)&KtH[r * 64 + ((quad ^ rx) ^ 4) * 8];
            f32x4 sa = {0, 0, 0, 0};
            sa = __builtin_amdgcn_mfma_f32_16x16x32_bf16(kf0, qf0, sa, 0, 0, 0);
            sa = __builtin_amdgcn_mfma_f32_16x16x32_bf16(kf1, qf1, sa, 0, 0, 0);
            const unsigned nib = (unsigned)(mq >> (st * 16)) & 0xFu;
            float p0 = (nib & 1u) ? exp2f(sa[0]) : 0.f;
            float p1 = (nib & 2u) ? exp2f(sa[1]) : 0.f;
            float p2 = (nib & 4u) ? exp2f(sa[2]) : 0.f;
            float p3 = (nib & 8u) ? exp2f(sa[3]) : 0.f;
            union { unsigned u2[2]; bf16x4 v; } pu;
            pu.u2[0] = pk2bf(p0, p1);
            pu.u2[1] = pk2bf(p2, p3);
            p[st] = pu.v;
            Osum = __builtin_amdgcn_mfma_f32_16x16x16bf16_1k(p[st], ones, Osum, 0, 0, 0);
        }

        // ---- PV: O[dt] += P * V (B-frags in registers from L2) ----
#pragma unroll
        for (int dt = 0; dt < 4; ++dt)
#pragma unroll
            for (int st = 0; st < 4; ++st)
                O[dt] = __builtin_amdgcn_mfma_f32_16x16x16bf16_1k(p[st], vb[dt][st], O[dt], 0, 0, 0);

        __syncthreads();   // readers done with K buf(kt); drains DMA(kt+1) post-compute
    }

    // ---- epilogue: direct store, wave-local denominator ----
    float inv[4];
#pragma unroll
    for (int r = 0; r < 4; ++r) inv[r] = 1.0f / Osum[r];
#pragma unroll
    for (int r = 0; r < 4; ++r) {
        const int row = q0 + w * 16 + quad * 4 + r;
        unsigned short* dst = ctx + ((size_t)bh * SEQ + row) * DH + l15;
#pragma unroll
        for (int dt = 0; dt < 4; ++dt)
            dst[dt * 16] = f2bf(O[dt][r] * inv[r]);
    }
}

// ---------------------------------------------------------------------------
// Kernel 3: output projection via MFMA, DMA-staged + double-buffered.
// (frozen)
// ---------------------------------------------------------------------------
__global__ __launch_bounds__(256, 4) void outproj_mfma(
    const unsigned short* __restrict__ ctx, const unsigned short* __restrict__ Wob,
    const float* __restrict__ bo, float* __restrict__ out)
{
    const int n0 = blockIdx.x * 64;
    const int m0 = blockIdx.y * 64;
    const int b  = m0 / SEQ;
    const int s0 = m0 % SEQ;

    __shared__ unsigned char smem[32768];   // buf(16K) x2: [A 8K | W 8K]

    const int t    = threadIdx.x;
    const int w    = t >> 6;
    const int lane = t & 63;
    const int l15  = lane & 15;
    const int quad = lane >> 4;
    const int srow   = lane >> 3;
    const int schunk = (lane & 7) ^ srow;

    const unsigned short* abase = ctx + ((size_t)b * HEADS * SEQ + s0 + srow) * DH + schunk * 8;
    const unsigned short* wbase = Wob + (size_t)(n0 + srow) * EMBED + schunk * 8;

    f32x4 acc[4] = {f32x4{0,0,0,0}, f32x4{0,0,0,0}, f32x4{0,0,0,0}, f32x4{0,0,0,0}};

    {
        unsigned char* Ab = smem;
        unsigned char* Wb = smem + 8192;
#pragma unroll
        for (int j = 0; j < 4; ++j) {
            const int idx = w * 4 + j;
            if (idx < 8)
                gl_lds16(abase + (size_t)idx * 8 * DH, Ab + idx * 1024);
            else
                gl_lds16(wbase + (size_t)(idx - 8) * 8 * EMBED, Wb + (idx - 8) * 1024);
        }
    }
    __syncthreads();

    for (int kt = 0; kt < 16; ++kt) {
        if (kt < 15) {
            const int ktn = kt + 1;
            unsigned char* Ab = smem + (ktn & 1) * 16384;
            unsigned char* Wb = Ab + 8192;
#pragma unroll
            for (int j = 0; j < 4; ++j) {
                const int idx = w * 4 + j;
                if (idx < 8)
                    gl_lds16(abase + (size_t)ktn * SEQ * DH + (size_t)idx * 8 * DH,
                             Ab + idx * 1024);
                else
                    gl_lds16(wbase + (size_t)(idx - 8) * 8 * EMBED + ktn * 64,
                             Wb + (idx - 8) * 1024);
            }
        }

        const unsigned short* At = (const unsigned short*)(smem + (kt & 1) * 16384);
        const unsigned short* Wt = At + 4096;
        const int rx = l15 & 7;
        const int c0 = ((quad ^ rx)) * 8;

        bf16x8 bf0 = *(const bf16x8*)&Wt[(w * 16 + l15) * 64 + c0];
        bf16x8 bf1 = *(const bf16x8*)&Wt[(w * 16 + l15) * 64 + (c0 ^ 32)];
#pragma unroll
        for (int mt = 0; mt < 4; ++mt) {
            bf16x8 af0 = *(const bf16x8*)&At[(mt * 16 + l15) * 64 + c0];
            bf16x8 af1 = *(const bf16x8*)&At[(mt * 16 + l15) * 64 + (c0 ^ 32)];
            acc[mt] = __builtin_amdgcn_mfma_f32_16x16x32_bf16(af0, bf0, acc[mt], 0, 0, 0);
            acc[mt] = __builtin_amdgcn_mfma_f32_16x16x32_bf16(af1, bf1, acc[mt], 0, 0, 0);
        }
        __syncthreads();
    }

    const float bv = bo[n0 + w * 16 + l15];
#pragma unroll
    for (int mt = 0; mt < 4; ++mt) {
#pragma unroll
        for (int r = 0; r < 4; ++r) {
            out[(size_t)(m0 + mt * 16 + quad * 4 + r) * EMBED + n0 + w * 16 + l15] =
                acc[mt][r] + bv;
        }
    }
}

// ---------------------------------------------------------------------------
extern "C" void kernel_launch(void* const* d_in, const int* in_sizes, int n_in,
                              void* d_out, int out_size, void* d_ws, size_t ws_size,
                              hipStream_t stream) {
    const float* k    = (const float*)d_in[0];
    const float* q    = (const float*)d_in[1];
    const float* v    = (const float*)d_in[2];
    const int*   mask = (const int*)  d_in[3];
    const float* Wk   = (const float*)d_in[4];
    const float* bk   = (const float*)d_in[5];
    const float* Wq   = (const float*)d_in[6];
    const float* bq   = (const float*)d_in[7];
    const float* Wv   = (const float*)d_in[8];
    const float* bv   = (const float*)d_in[9];
    const float* Wo   = (const float*)d_in[10];
    const float* bo   = (const float*)d_in[11];
    float* out = (float*)d_out;

    const size_t TEN = (size_t)BATCH * HEADS * SEQ * DH;   // 4,194,304 elems
    unsigned short* qh_bf = (unsigned short*)d_ws;         // 8 MB
    unsigned short* kh_bf = qh_bf + TEN;                   // 8 MB
    unsigned short* vp_bf = kh_bf + TEN;                   // 8 MB (fragment-major V)
    unsigned short* ctxb  = vp_bf + TEN;                   // 8 MB
    unsigned short* Wob   = ctxb + TEN;                    // 2 MB
    u64*            mbits = (u64*)(Wob + EMBED * EMBED);   // 1 MB  (35 MB total)

    proj_mfma<<<dim3(1024, 4), 256, 0, stream>>>(
        q, k, v, Wq, bq, Wk, bk, Wv, bv,
        qh_bf, kh_bf, vp_bf, mask, mbits, Wo, Wob);
    attn_kernel<<<dim3((SEQ / 64) * BATCH * HEADS), 256, 0, stream>>>(
        qh_bf, kh_bf, vp_bf, mbits, ctxb);
    outproj_mfma<<<dim3(EMBED / 64, BATCH * SEQ / 64), 256, 0, stream>>>(
        ctxb, Wob, bo, out);
}

// Round 8
// 229.964 us; speedup vs baseline: 1.0883x; 1.0883x over previous
//
#include <hip/hip_runtime.h>
#include <hip/hip_bf16.h>
#include <math.h>

#define EMBED 1024
#define HEADS 16
#define DH    64
#define BATCH 2
#define SEQ   2048

typedef __attribute__((ext_vector_type(8))) short bf16x8;
typedef __attribute__((ext_vector_type(4))) short bf16x4;
typedef __attribute__((ext_vector_type(4))) float f32x4;
typedef unsigned long long u64;

#define QSCALE 0.1803368801111244f   // 0.125 * log2(e): exp(s/8) == exp2(s*QSCALE)

static __device__ __forceinline__ unsigned short f2bf(float x) {
    unsigned u = __builtin_bit_cast(unsigned, x);
    return (unsigned short)((u + 0x7fffu + ((u >> 16) & 1u)) >> 16);
}
static __device__ __forceinline__ unsigned pk2bf(float a, float b) {
    union { __hip_bfloat162 h2; unsigned u; } c;
    c.h2 = __float22bfloat162_rn(make_float2(a, b));
    return c.u;
}
// async global->LDS DMA, 16 B per lane; LDS dest = wave-uniform base + lane*16
static __device__ __forceinline__ void gl_lds16(const void* g, void* l) {
    __builtin_amdgcn_global_load_lds(
        (const __attribute__((address_space(1))) void*)g,
        (__attribute__((address_space(3))) void*)l, 16, 0, 0);
}
// convert 16 consecutive fp32 (two float4 pairs) to one bf16x8 fragment
static __device__ __forceinline__ bf16x8 cvt8(const float* p) {
    float4 a = ((const float4*)p)[0];
    float4 b = ((const float4*)p)[1];
    union { unsigned u[4]; bf16x8 v; } c;
    c.u[0] = pk2bf(a.x, a.y); c.u[1] = pk2bf(a.z, a.w);
    c.u[2] = pk2bf(b.x, b.y); c.u[3] = pk2bf(b.z, b.w);
    return c.v;
}

// ---------------------------------------------------------------------------
// Kernel 1 (mega-proj, R5 version): grid = (1024, 4), block = 256.
//   which 0: Q projection, C = X·W^T, out [B,H,S,DH] (R4 hybrid).
//   which 1: K projection, C = X·W^T, out [B,H,S,DH].
//   which 2: V projection TRANSPOSED, C = W·X^T -> vt[bh][d][s].
//   which 3: blk<512 maskpack | blk>=512 Wo fp32->bf16.
// ---------------------------------------------------------------------------
__global__ __launch_bounds__(256) void proj_mfma(
    const float* __restrict__ q, const float* __restrict__ k, const float* __restrict__ v,
    const float* __restrict__ Wq, const float* __restrict__ bq,
    const float* __restrict__ Wk, const float* __restrict__ bk,
    const float* __restrict__ Wv, const float* __restrict__ bv,
    unsigned short* __restrict__ qh, unsigned short* __restrict__ kh,
    unsigned short* __restrict__ vt,
    const int* __restrict__ mask, u64* __restrict__ bits,
    const float* __restrict__ Wo, unsigned short* __restrict__ Wob)
{
    const int blk   = blockIdx.x;
    const int which = blockIdx.y;
    const int t     = threadIdx.x;

    if (which == 3) {                     // ---- prep jobs (no LDS, no barrier) ----
        if (blk < 512) {                  // mask -> bitmask
            const int idx = blk * 256 + t;
            const int4* src = (const int4*)(mask + (size_t)idx * 64);
            u64 wb = 0;
#pragma unroll
            for (int u = 0; u < 16; ++u) {
                int4 m = src[u];
                u64 nib = (m.x != 0 ? 1ull : 0) | (m.y != 0 ? 2ull : 0) |
                          (m.z != 0 ? 4ull : 0) | (m.w != 0 ? 8ull : 0);
                wb |= nib << (u * 4);
            }
            bits[idx] = wb;
        } else {                          // Wo fp32 -> bf16
            const int i = ((blk - 512) * 256 + t) * 8;
            float4 a = ((const float4*)(Wo + i))[0];
            float4 b = ((const float4*)(Wo + i))[1];
            unsigned o32[4] = {pk2bf(a.x, a.y), pk2bf(a.z, a.w),
                               pk2bf(b.x, b.y), pk2bf(b.z, b.w)};
            *(uint4*)(Wob + i) = *(uint4*)o32;
        }
        return;
    }

    const float* x; const float* W; const float* bias;
    if (which == 0)      { x = q; W = Wq; bias = bq; }
    else if (which == 1) { x = k; W = Wk; bias = bk; }
    else                 { x = v; W = Wv; bias = bv; }

    __shared__ unsigned short Ws[64 * 72];

    const int w    = t >> 6;
    const int lane = t & 63;
    const int l15  = lane & 15;
    const int quad = lane >> 4;

    // ---- stage W into LDS (cooperative, one pass; verified R2 layout) ----
    const int sr = t >> 2, sp = t & 3;
    {
        const float* wsrc = W + (size_t)sr * 64 + sp * 16;
        unsigned o32[8];
#pragma unroll
        for (int u4 = 0; u4 < 4; ++u4) {
            float4 a = ((const float4*)wsrc)[u4];
            o32[u4 * 2 + 0] = pk2bf(a.x, a.y);
            o32[u4 * 2 + 1] = pk2bf(a.z, a.w);
        }
        *(uint4*)&Ws[sr * 72 + sp * 16]     = *(uint4*)&o32[0];
        *(uint4*)&Ws[sr * 72 + sp * 16 + 8] = *(uint4*)&o32[4];
    }

    if (which == 2) {                     // ---- V: C = W·X^T -> vt[bh][d][s] ----
        const int bh = blk >> 5;          // (b,h) 0..31
        const int st = blk & 31;          // s-tile
        const int b  = bh >> 4, h = bh & 15;
        const int s  = st * 64 + w * 16 + l15;

        const float* xrow = x + ((size_t)(b * SEQ + s)) * EMBED + h * DH;
        const bf16x8 bx0 = cvt8(xrow + quad * 8);
        const bf16x8 bx1 = cvt8(xrow + 32 + quad * 8);

        __syncthreads();

#pragma unroll
        for (int nt = 0; nt < 4; ++nt) {
            bf16x8 aw0 = *(const bf16x8*)&Ws[(nt * 16 + l15) * 72 + quad * 8];
            bf16x8 aw1 = *(const bf16x8*)&Ws[(nt * 16 + l15) * 72 + 32 + quad * 8];
            f32x4 a = {0, 0, 0, 0};
            a = __builtin_amdgcn_mfma_f32_16x16x32_bf16(aw0, bx0, a, 0, 0, 0);
            a = __builtin_amdgcn_mfma_f32_16x16x32_bf16(aw1, bx1, a, 0, 0, 0);
#pragma unroll
            for (int r = 0; r < 4; ++r) {
                const int d = nt * 16 + quad * 4 + r;
                vt[((size_t)bh * DH + d) * SEQ + s] = f2bf(a[r] + bias[d]);
            }
        }
        return;
    }

    // ---- Q/K: C = X·W^T (R4 hybrid path) ----
    const float oscale = (which == 0) ? QSCALE : 1.0f;
    unsigned short* out = (which == 0) ? qh : kh;

    const float* xrow = x + ((size_t)blk * 64 + w * 16 + l15) * 64;
    const bf16x8 af0 = cvt8(xrow + quad * 8);
    const bf16x8 af1 = cvt8(xrow + 32 + quad * 8);

    __syncthreads();

    f32x4 acc[4];
#pragma unroll
    for (int nt = 0; nt < 4; ++nt) {
        bf16x8 bf0 = *(const bf16x8*)&Ws[(nt * 16 + l15) * 72 + quad * 8];
        bf16x8 bf1 = *(const bf16x8*)&Ws[(nt * 16 + l15) * 72 + 32 + quad * 8];
        f32x4 a = {0, 0, 0, 0};
        a = __builtin_amdgcn_mfma_f32_16x16x32_bf16(af0, bf0, a, 0, 0, 0);
        a = __builtin_amdgcn_mfma_f32_16x16x32_bf16(af1, bf1, a, 0, 0, 0);
        acc[nt] = a;
    }

    const int bsidx = blk * 4 + w;
    const int b = bsidx >> 11, s = bsidx & 2047;
#pragma unroll
    for (int nt = 0; nt < 4; ++nt) {
        const int d = nt * 16 + l15;
        const float bb = bias[d];
#pragma unroll
        for (int r = 0; r < 4; ++r) {
            const int h = quad * 4 + r;
            out[(((size_t)b * HEADS + h) * SEQ + s) * DH + d] =
                f2bf((acc[nt][r] + bb) * oscale);
        }
    }
}

// ---------------------------------------------------------------------------
// Kernel 2 (R8): MFMA flash attention — R2 per-wave code, 8-wave blocks.
// 512 threads = 8 waves, each owning 16 q-rows of a 128-row Q panel; one
// staged K/V tile (16KB, double-buffered = 32KB LDS) serves 8 waves instead
// of 4 -> per-CU DMA behind each barrier drain HALVES (2 blocks x 16KB vs
// 4 x 16KB), K/V L2 re-read traffic halves. Per-wave fragments, swizzles,
// softmax, PV path bit-identical to the verified 85us R2 kernel.
// grid = flat 512; bh = bid & 31 for XCD-local K/V reuse.
// ---------------------------------------------------------------------------
__global__ __launch_bounds__(512, 4) void attn_kernel(
    const unsigned short* __restrict__ qh, const unsigned short* __restrict__ kh,
    const unsigned short* __restrict__ vt, const u64* __restrict__ mbits,
    unsigned short* __restrict__ ctx)
{
    const int bid = blockIdx.x;
    const int bh  = bid & 31;
    const int q0  = (bid >> 5) * 128;     // 128-row Q panel
    const int b   = bh >> 4;

    __shared__ unsigned char smem[32768];   // buf(16K) x2: [K 8K | V 8K]

    const int t    = threadIdx.x;
    const int w    = t >> 6;              // wave id 0..7: q-subtile (16 rows)
    const int lane = t & 63;
    const int l15  = lane & 15;
    const int quad = lane >> 4;

    const int srow   = lane >> 3;
    const int schunk = (lane & 7) ^ srow;

    const unsigned short* qb = qh + ((size_t)bh * SEQ + q0 + w * 16 + l15) * DH + quad * 8;
    const bf16x8 qf0 = *(const bf16x8*)qb;
    const bf16x8 qf1 = *(const bf16x8*)(qb + 32);

    f32x4 O[4];
#pragma unroll
    for (int dt = 0; dt < 4; ++dt) O[dt] = f32x4{0, 0, 0, 0};
    f32x4 Osum = {0, 0, 0, 0};
    const bf16x4 ones = {(short)0x3F80, (short)0x3F80, (short)0x3F80, (short)0x3F80};

    const unsigned short* kbase = kh + (size_t)bh * SEQ * DH
                                  + (size_t)srow * DH + schunk * 8;
    const unsigned short* vbase = vt + (size_t)bh * DH * SEQ
                                  + (size_t)srow * SEQ + schunk * 8;
    const u64* mrow = mbits + ((size_t)b * SEQ + q0 + w * 16 + l15) * (SEQ / 64);

    // issue DMA for tile 0 into buf 0: waves 0-3 stage K, waves 4-7 stage V
    if (w < 4) {
        unsigned char* Kd = smem;
#pragma unroll
        for (int j = 0; j < 2; ++j) {
            const int i = w * 2 + j;
            gl_lds16(kbase + (size_t)i * 8 * DH, Kd + i * 1024);
        }
    } else {
        unsigned char* Vd = smem + 8192;
#pragma unroll
        for (int j = 0; j < 2; ++j) {
            const int i = (w - 4) * 2 + j;
            gl_lds16(vbase + (size_t)i * 8 * SEQ, Vd + i * 1024);
        }
    }
    u64 pm = mrow[0];
    __syncthreads();                      // drains DMA(0)

    for (int kt = 0; kt < 32; ++kt) {
        // ---- issue DMA for tile kt+1 into the other buffer ----
        if (kt < 31) {
            const int bn = (kt + 1) & 1;
            if (w < 4) {
                unsigned char* Kd = smem + bn * 16384;
                const unsigned short* g0 = kbase + (size_t)(kt + 1) * 64 * DH;
#pragma unroll
                for (int j = 0; j < 2; ++j) {
                    const int i = w * 2 + j;
                    gl_lds16(g0 + (size_t)i * 8 * DH, Kd + i * 1024);
                }
            } else {
                unsigned char* Vd = smem + bn * 16384 + 8192;
                const unsigned short* g0 = vbase + (kt + 1) * 64;
#pragma unroll
                for (int j = 0; j < 2; ++j) {
                    const int i = (w - 4) * 2 + j;
                    gl_lds16(g0 + (size_t)i * 8 * SEQ, Vd + i * 1024);
                }
            }
        }
        const u64 mb = pm;
        if (kt < 31) pm = mrow[kt + 1];

        const unsigned short* KtH = (const unsigned short*)(smem + (kt & 1) * 16384);
        const unsigned short* VtH = KtH + 4096;

        // ---- S^T tile + masked exp2; P stays in registers ----
        const u64 mq = mb >> (quad * 4);
        bf16x4 p[4];
        const int rx = l15 & 7;
#pragma unroll
        for (int st = 0; st < 4; ++st) {
            const int r = st * 16 + l15;
            bf16x8 kf0 = *(const bf16x8*)&KtH[r * 64 + ((quad ^ rx)) * 8];
            bf16x8 kf1 = *(const bf16x8*)&KtH[r * 64 + ((quad ^ rx) ^ 4) * 8];
            f32x4 sa = {0, 0, 0, 0};
            sa = __builtin_amdgcn_mfma_f32_16x16x32_bf16(kf0, qf0, sa, 0, 0, 0);
            sa = __builtin_amdgcn_mfma_f32_16x16x32_bf16(kf1, qf1, sa, 0, 0, 0);
            const unsigned nib = (unsigned)(mq >> (st * 16)) & 0xFu;
            float p0 = (nib & 1u) ? exp2f(sa[0]) : 0.f;
            float p1 = (nib & 2u) ? exp2f(sa[1]) : 0.f;
            float p2 = (nib & 4u) ? exp2f(sa[2]) : 0.f;
            float p3 = (nib & 8u) ? exp2f(sa[3]) : 0.f;
            union { unsigned u2[2]; bf16x4 v; } pu;
            pu.u2[0] = pk2bf(p0, p1);
            pu.u2[1] = pk2bf(p2, p3);
            p[st] = pu.v;
            Osum = __builtin_amdgcn_mfma_f32_16x16x16bf16_1k(p[st], ones, Osum, 0, 0, 0);
        }

        // ---- PV: O[dt] += P * V (B-frags from swizzled Vt) ----
#pragma unroll
        for (int dt = 0; dt < 4; ++dt) {
            const int d = dt * 16 + l15;
            const int dx = l15 & 7;
#pragma unroll
            for (int st = 0; st < 4; ++st) {
                const int ch = (st * 2 + (quad >> 1)) ^ dx;
                bf16x4 vb = *(const bf16x4*)&VtH[d * 64 + ch * 8 + (quad & 1) * 4];
                O[dt] = __builtin_amdgcn_mfma_f32_16x16x16bf16_1k(p[st], vb, O[dt], 0, 0, 0);
            }
        }
        __syncthreads();   // readers done with buf(kt); drains DMA(kt+1) post-compute
    }

    // ---- epilogue: direct store, wave-local denominator ----
    float inv[4];
#pragma unroll
    for (int r = 0; r < 4; ++r) inv[r] = 1.0f / Osum[r];
#pragma unroll
    for (int r = 0; r < 4; ++r) {
        const int row = q0 + w * 16 + quad * 4 + r;
        unsigned short* dst = ctx + ((size_t)bh * SEQ + row) * DH + l15;
#pragma unroll
        for (int dt = 0; dt < 4; ++dt)
            dst[dt * 16] = f2bf(O[dt][r] * inv[r]);
    }
}

// ---------------------------------------------------------------------------
// Kernel 3: output projection via MFMA, DMA-staged + double-buffered.
// (frozen)
// ---------------------------------------------------------------------------
__global__ __launch_bounds__(256, 4) void outproj_mfma(
    const unsigned short* __restrict__ ctx, const unsigned short* __restrict__ Wob,
    const float* __restrict__ bo, float* __restrict__ out)
{
    const int n0 = blockIdx.x * 64;
    const int m0 = blockIdx.y * 64;
    const int b  = m0 / SEQ;
    const int s0 = m0 % SEQ;

    __shared__ unsigned char smem[32768];   // buf(16K) x2: [A 8K | W 8K]

    const int t    = threadIdx.x;
    const int w    = t >> 6;
    const int lane = t & 63;
    const int l15  = lane & 15;
    const int quad = lane >> 4;
    const int srow   = lane >> 3;
    const int schunk = (lane & 7) ^ srow;

    const unsigned short* abase = ctx + ((size_t)b * HEADS * SEQ + s0 + srow) * DH + schunk * 8;
    const unsigned short* wbase = Wob + (size_t)(n0 + srow) * EMBED + schunk * 8;

    f32x4 acc[4] = {f32x4{0,0,0,0}, f32x4{0,0,0,0}, f32x4{0,0,0,0}, f32x4{0,0,0,0}};

    {
        unsigned char* Ab = smem;
        unsigned char* Wb = smem + 8192;
#pragma unroll
        for (int j = 0; j < 4; ++j) {
            const int idx = w * 4 + j;
            if (idx < 8)
                gl_lds16(abase + (size_t)idx * 8 * DH, Ab + idx * 1024);
            else
                gl_lds16(wbase + (size_t)(idx - 8) * 8 * EMBED, Wb + (idx - 8) * 1024);
        }
    }
    __syncthreads();

    for (int kt = 0; kt < 16; ++kt) {
        if (kt < 15) {
            const int ktn = kt + 1;
            unsigned char* Ab = smem + (ktn & 1) * 16384;
            unsigned char* Wb = Ab + 8192;
#pragma unroll
            for (int j = 0; j < 4; ++j) {
                const int idx = w * 4 + j;
                if (idx < 8)
                    gl_lds16(abase + (size_t)ktn * SEQ * DH + (size_t)idx * 8 * DH,
                             Ab + idx * 1024);
                else
                    gl_lds16(wbase + (size_t)(idx - 8) * 8 * EMBED + ktn * 64,
                             Wb + (idx - 8) * 1024);
            }
        }

        const unsigned short* At = (const unsigned short*)(smem + (kt & 1) * 16384);
        const unsigned short* Wt = At + 4096;
        const int rx = l15 & 7;
        const int c0 = ((quad ^ rx)) * 8;

        bf16x8 bf0 = *(const bf16x8*)&Wt[(w * 16 + l15) * 64 + c0];
        bf16x8 bf1 = *(const bf16x8*)&Wt[(w * 16 + l15) * 64 + (c0 ^ 32)];
#pragma unroll
        for (int mt = 0; mt < 4; ++mt) {
            bf16x8 af0 = *(const bf16x8*)&At[(mt * 16 + l15) * 64 + c0];
            bf16x8 af1 = *(const bf16x8*)&At[(mt * 16 + l15) * 64 + (c0 ^ 32)];
            acc[mt] = __builtin_amdgcn_mfma_f32_16x16x32_bf16(af0, bf0, acc[mt], 0, 0, 0);
            acc[mt] = __builtin_amdgcn_mfma_f32_16x16x32_bf16(af1, bf1, acc[mt], 0, 0, 0);
        }
        __syncthreads();
    }

    const float bv = bo[n0 + w * 16 + l15];
#pragma unroll
    for (int mt = 0; mt < 4; ++mt) {
#pragma unroll
        for (int r = 0; r < 4; ++r) {
            out[(size_t)(m0 + mt * 16 + quad * 4 + r) * EMBED + n0 + w * 16 + l15] =
                acc[mt][r] + bv;
        }
    }
}

// ---------------------------------------------------------------------------
extern "C" void kernel_launch(void* const* d_in, const int* in_sizes, int n_in,
                              void* d_out, int out_size, void* d_ws, size_t ws_size,
                              hipStream_t stream) {
    const float* k    = (const float*)d_in[0];
    const float* q    = (const float*)d_in[1];
    const float* v    = (const float*)d_in[2];
    const int*   mask = (const int*)  d_in[3];
    const float* Wk   = (const float*)d_in[4];
    const float* bk   = (const float*)d_in[5];
    const float* Wq   = (const float*)d_in[6];
    const float* bq   = (const float*)d_in[7];
    const float* Wv   = (const float*)d_in[8];
    const float* bv   = (const float*)d_in[9];
    const float* Wo   = (const float*)d_in[10];
    const float* bo   = (const float*)d_in[11];
    float* out = (float*)d_out;

    const size_t TEN = (size_t)BATCH * HEADS * SEQ * DH;   // 4,194,304 elems
    unsigned short* qh_bf = (unsigned short*)d_ws;         // 8 MB
    unsigned short* kh_bf = qh_bf + TEN;                   // 8 MB
    unsigned short* vt_bf = kh_bf + TEN;                   // 8 MB
    unsigned short* ctxb  = vt_bf + TEN;                   // 8 MB
    unsigned short* Wob   = ctxb + TEN;                    // 2 MB
    u64*            mbits = (u64*)(Wob + EMBED * EMBED);   // 1 MB  (35 MB total)

    proj_mfma<<<dim3(1024, 4), 256, 0, stream>>>(
        q, k, v, Wq, bq, Wk, bk, Wv, bv,
        qh_bf, kh_bf, vt_bf, mask, mbits, Wo, Wob);
    attn_kernel<<<dim3((SEQ / 128) * BATCH * HEADS), 512, 0, stream>>>(
        qh_bf, kh_bf, vt_bf, mbits, ctxb);
    outproj_mfma<<<dim3(EMBED / 64, BATCH * SEQ / 64), 256, 0, stream>>>(
        ctxb, Wob, bo, out);
}

// Round 9
// 216.198 us; speedup vs baseline: 1.1576x; 1.0637x over previous
//
#include <hip/hip_runtime.h>
#include <hip/hip_bf16.h>
#include <math.h>

#define EMBED 1024
#define HEADS 16
#define DH    64
#define BATCH 2
#define SEQ   2048

typedef __attribute__((ext_vector_type(8))) short bf16x8;
typedef __attribute__((ext_vector_type(4))) short bf16x4;
typedef __attribute__((ext_vector_type(4))) float f32x4;
typedef unsigned long long u64;

#define QSCALE 0.1803368801111244f   // 0.125 * log2(e): exp(s/8) == exp2(s*QSCALE)

static __device__ __forceinline__ unsigned short f2bf(float x) {
    unsigned u = __builtin_bit_cast(unsigned, x);
    return (unsigned short)((u + 0x7fffu + ((u >> 16) & 1u)) >> 16);
}
static __device__ __forceinline__ unsigned pk2bf(float a, float b) {
    union { __hip_bfloat162 h2; unsigned u; } c;
    c.h2 = __float22bfloat162_rn(make_float2(a, b));
    return c.u;
}
// raw hardware exp2 (single v_exp_f32; skips libm guard sequence)
static __device__ __forceinline__ float fexp2(float x) {
#if __has_builtin(__builtin_amdgcn_exp2f)
    return __builtin_amdgcn_exp2f(x);
#else
    float r; asm("v_exp_f32 %0, %1" : "=v"(r) : "v"(x)); return r;
#endif
}
// async global->LDS DMA, 16 B per lane; LDS dest = wave-uniform base + lane*16
static __device__ __forceinline__ void gl_lds16(const void* g, void* l) {
    __builtin_amdgcn_global_load_lds(
        (const __attribute__((address_space(1))) void*)g,
        (__attribute__((address_space(3))) void*)l, 16, 0, 0);
}
// convert 16 consecutive fp32 (two float4 pairs) to one bf16x8 fragment
static __device__ __forceinline__ bf16x8 cvt8(const float* p) {
    float4 a = ((const float4*)p)[0];
    float4 b = ((const float4*)p)[1];
    union { unsigned u[4]; bf16x8 v; } c;
    c.u[0] = pk2bf(a.x, a.y); c.u[1] = pk2bf(a.z, a.w);
    c.u[2] = pk2bf(b.x, b.y); c.u[3] = pk2bf(b.z, b.w);
    return c.v;
}

// ---------------------------------------------------------------------------
// Kernel 1 (mega-proj, frozen since R5): grid = (1024, 4), block = 256.
//   which 0: Q projection, C = X·W^T, out [B,H,S,DH] (R4 hybrid).
//   which 1: K projection, C = X·W^T, out [B,H,S,DH].
//   which 2: V projection TRANSPOSED, C = W·X^T -> vt[bh][d][s].
//   which 3: blk<512 maskpack | blk>=512 Wo fp32->bf16.
// ---------------------------------------------------------------------------
__global__ __launch_bounds__(256) void proj_mfma(
    const float* __restrict__ q, const float* __restrict__ k, const float* __restrict__ v,
    const float* __restrict__ Wq, const float* __restrict__ bq,
    const float* __restrict__ Wk, const float* __restrict__ bk,
    const float* __restrict__ Wv, const float* __restrict__ bv,
    unsigned short* __restrict__ qh, unsigned short* __restrict__ kh,
    unsigned short* __restrict__ vt,
    const int* __restrict__ mask, u64* __restrict__ bits,
    const float* __restrict__ Wo, unsigned short* __restrict__ Wob)
{
    const int blk   = blockIdx.x;
    const int which = blockIdx.y;
    const int t     = threadIdx.x;

    if (which == 3) {                     // ---- prep jobs (no LDS, no barrier) ----
        if (blk < 512) {                  // mask -> bitmask
            const int idx = blk * 256 + t;
            const int4* src = (const int4*)(mask + (size_t)idx * 64);
            u64 wb = 0;
#pragma unroll
            for (int u = 0; u < 16; ++u) {
                int4 m = src[u];
                u64 nib = (m.x != 0 ? 1ull : 0) | (m.y != 0 ? 2ull : 0) |
                          (m.z != 0 ? 4ull : 0) | (m.w != 0 ? 8ull : 0);
                wb |= nib << (u * 4);
            }
            bits[idx] = wb;
        } else {                          // Wo fp32 -> bf16
            const int i = ((blk - 512) * 256 + t) * 8;
            float4 a = ((const float4*)(Wo + i))[0];
            float4 b = ((const float4*)(Wo + i))[1];
            unsigned o32[4] = {pk2bf(a.x, a.y), pk2bf(a.z, a.w),
                               pk2bf(b.x, b.y), pk2bf(b.z, b.w)};
            *(uint4*)(Wob + i) = *(uint4*)o32;
        }
        return;
    }

    const float* x; const float* W; const float* bias;
    if (which == 0)      { x = q; W = Wq; bias = bq; }
    else if (which == 1) { x = k; W = Wk; bias = bk; }
    else                 { x = v; W = Wv; bias = bv; }

    __shared__ unsigned short Ws[64 * 72];

    const int w    = t >> 6;
    const int lane = t & 63;
    const int l15  = lane & 15;
    const int quad = lane >> 4;

    // ---- stage W into LDS (cooperative, one pass; verified R2 layout) ----
    const int sr = t >> 2, sp = t & 3;
    {
        const float* wsrc = W + (size_t)sr * 64 + sp * 16;
        unsigned o32[8];
#pragma unroll
        for (int u4 = 0; u4 < 4; ++u4) {
            float4 a = ((const float4*)wsrc)[u4];
            o32[u4 * 2 + 0] = pk2bf(a.x, a.y);
            o32[u4 * 2 + 1] = pk2bf(a.z, a.w);
        }
        *(uint4*)&Ws[sr * 72 + sp * 16]     = *(uint4*)&o32[0];
        *(uint4*)&Ws[sr * 72 + sp * 16 + 8] = *(uint4*)&o32[4];
    }

    if (which == 2) {                     // ---- V: C = W·X^T -> vt[bh][d][s] ----
        const int bh = blk >> 5;          // (b,h) 0..31
        const int st = blk & 31;          // s-tile
        const int b  = bh >> 4, h = bh & 15;
        const int s  = st * 64 + w * 16 + l15;

        const float* xrow = x + ((size_t)(b * SEQ + s)) * EMBED + h * DH;
        const bf16x8 bx0 = cvt8(xrow + quad * 8);
        const bf16x8 bx1 = cvt8(xrow + 32 + quad * 8);

        __syncthreads();

#pragma unroll
        for (int nt = 0; nt < 4; ++nt) {
            bf16x8 aw0 = *(const bf16x8*)&Ws[(nt * 16 + l15) * 72 + quad * 8];
            bf16x8 aw1 = *(const bf16x8*)&Ws[(nt * 16 + l15) * 72 + 32 + quad * 8];
            f32x4 a = {0, 0, 0, 0};
            a = __builtin_amdgcn_mfma_f32_16x16x32_bf16(aw0, bx0, a, 0, 0, 0);
            a = __builtin_amdgcn_mfma_f32_16x16x32_bf16(aw1, bx1, a, 0, 0, 0);
#pragma unroll
            for (int r = 0; r < 4; ++r) {
                const int d = nt * 16 + quad * 4 + r;
                vt[((size_t)bh * DH + d) * SEQ + s] = f2bf(a[r] + bias[d]);
            }
        }
        return;
    }

    // ---- Q/K: C = X·W^T (R4 hybrid path) ----
    const float oscale = (which == 0) ? QSCALE : 1.0f;
    unsigned short* out = (which == 0) ? qh : kh;

    const float* xrow = x + ((size_t)blk * 64 + w * 16 + l15) * 64;
    const bf16x8 af0 = cvt8(xrow + quad * 8);
    const bf16x8 af1 = cvt8(xrow + 32 + quad * 8);

    __syncthreads();

    f32x4 acc[4];
#pragma unroll
    for (int nt = 0; nt < 4; ++nt) {
        bf16x8 bf0 = *(const bf16x8*)&Ws[(nt * 16 + l15) * 72 + quad * 8];
        bf16x8 bf1 = *(const bf16x8*)&Ws[(nt * 16 + l15) * 72 + 32 + quad * 8];
        f32x4 a = {0, 0, 0, 0};
        a = __builtin_amdgcn_mfma_f32_16x16x32_bf16(af0, bf0, a, 0, 0, 0);
        a = __builtin_amdgcn_mfma_f32_16x16x32_bf16(af1, bf1, a, 0, 0, 0);
        acc[nt] = a;
    }

    const int bsidx = blk * 4 + w;
    const int b = bsidx >> 11, s = bsidx & 2047;
#pragma unroll
    for (int nt = 0; nt < 4; ++nt) {
        const int d = nt * 16 + l15;
        const float bb = bias[d];
#pragma unroll
        for (int r = 0; r < 4; ++r) {
            const int h = quad * 4 + r;
            out[(((size_t)b * HEADS + h) * SEQ + s) * DH + d] =
                f2bf((acc[nt][r] + bb) * oscale);
        }
    }
}

// ---------------------------------------------------------------------------
// Kernel 2 (R9): MFMA flash attention — 8-wave blocks, K-STEP 128.
// Two 64-key subtiles per LDS buffer -> 16 barrier drains instead of 32
// (R8 showed the drain is latency-bound, not volume-bound: halve the COUNT).
// LDS = 2 bufs x 32KB [K0|K1|V0|V1] = 64KB; 512-thr blocks -> 2 blocks/CU
// = 16 waves/CU (same occupancy as R8). Per-subtile compute bit-identical
// to R2/R8. exp2 via raw v_exp_f32; s_setprio(1) around compute.
// grid = flat 512; bh = bid & 31 for XCD-local K/V reuse.
// ---------------------------------------------------------------------------
__global__ __launch_bounds__(512, 4) void attn_kernel(
    const unsigned short* __restrict__ qh, const unsigned short* __restrict__ kh,
    const unsigned short* __restrict__ vt, const u64* __restrict__ mbits,
    unsigned short* __restrict__ ctx)
{
    const int bid = blockIdx.x;
    const int bh  = bid & 31;
    const int q0  = (bid >> 5) * 128;     // 128-row Q panel
    const int b   = bh >> 4;

    __shared__ unsigned char smem[65536];   // buf(32K) x2: [K0 8K|K1 8K|V0 8K|V1 8K]

    const int t    = threadIdx.x;
    const int w    = t >> 6;              // wave id 0..7: q-subtile (16 rows)
    const int lane = t & 63;
    const int l15  = lane & 15;
    const int quad = lane >> 4;

    const int srow   = lane >> 3;
    const int schunk = (lane & 7) ^ srow;

    const unsigned short* qb = qh + ((size_t)bh * SEQ + q0 + w * 16 + l15) * DH + quad * 8;
    const bf16x8 qf0 = *(const bf16x8*)qb;
    const bf16x8 qf1 = *(const bf16x8*)(qb + 32);

    f32x4 O[4];
#pragma unroll
    for (int dt = 0; dt < 4; ++dt) O[dt] = f32x4{0, 0, 0, 0};
    f32x4 Osum = {0, 0, 0, 0};
    const bf16x4 ones = {(short)0x3F80, (short)0x3F80, (short)0x3F80, (short)0x3F80};

    const unsigned short* kbase = kh + (size_t)bh * SEQ * DH
                                  + (size_t)srow * DH + schunk * 8;
    const unsigned short* vbase = vt + (size_t)bh * DH * SEQ
                                  + (size_t)srow * SEQ + schunk * 8;
    const u64* mrow = mbits + ((size_t)b * SEQ + q0 + w * 16 + l15) * (SEQ / 64);

    // stage key-pair kp (keys kp*128..+127) into buffer `buf`:
    // 32 x 1KB issues spread over 8 waves (4/wave). idx 0..15 = K, 16..31 = V.
    auto stage = [&](int kp, unsigned char* buf) {
#pragma unroll
        for (int j = 0; j < 4; ++j) {
            const int idx = w * 4 + j;
            if (idx < 16) {
                const int u = idx >> 3, i = idx & 7;
                gl_lds16(kbase + ((size_t)kp * 128 + u * 64 + i * 8) * DH,
                         buf + u * 8192 + i * 1024);
            } else {
                const int u = (idx - 16) >> 3, i = (idx - 16) & 7;
                gl_lds16(vbase + kp * 128 + u * 64 + (size_t)i * 8 * SEQ,
                         buf + 16384 + u * 8192 + i * 1024);
            }
        }
    };

    stage(0, smem);
    u64 pm0 = mrow[0], pm1 = mrow[1];
    __syncthreads();                      // drains DMA(0)

    for (int it = 0; it < 16; ++it) {
        if (it < 15) stage(it + 1, smem + ((it + 1) & 1) * 32768);
        const u64 mb0 = pm0, mb1 = pm1;
        if (it < 15) { pm0 = mrow[2 * it + 2]; pm1 = mrow[2 * it + 3]; }

        const unsigned char* buf = smem + (it & 1) * 32768;

        __builtin_amdgcn_s_setprio(1);
#pragma unroll
        for (int u = 0; u < 2; ++u) {
            const unsigned short* KtH = (const unsigned short*)(buf + u * 8192);
            const unsigned short* VtH = (const unsigned short*)(buf + 16384 + u * 8192);
            const u64 mq = (u ? mb1 : mb0) >> (quad * 4);

            // ---- S^T subtile + masked exp2; P stays in registers ----
            bf16x4 p[4];
            const int rx = l15 & 7;
#pragma unroll
            for (int st = 0; st < 4; ++st) {
                const int r = st * 16 + l15;
                bf16x8 kf0 = *(const bf16x8*)&KtH[r * 64 + ((quad ^ rx)) * 8];
                bf16x8 kf1 = *(const bf16x8*)&KtH[r * 64 + ((quad ^ rx) ^ 4) * 8];
                f32x4 sa = {0, 0, 0, 0};
                sa = __builtin_amdgcn_mfma_f32_16x16x32_bf16(kf0, qf0, sa, 0, 0, 0);
                sa = __builtin_amdgcn_mfma_f32_16x16x32_bf16(kf1, qf1, sa, 0, 0, 0);
                const unsigned nib = (unsigned)(mq >> (st * 16)) & 0xFu;
                float p0 = (nib & 1u) ? fexp2(sa[0]) : 0.f;
                float p1 = (nib & 2u) ? fexp2(sa[1]) : 0.f;
                float p2 = (nib & 4u) ? fexp2(sa[2]) : 0.f;
                float p3 = (nib & 8u) ? fexp2(sa[3]) : 0.f;
                union { unsigned u2[2]; bf16x4 v; } pu;
                pu.u2[0] = pk2bf(p0, p1);
                pu.u2[1] = pk2bf(p2, p3);
                p[st] = pu.v;
                Osum = __builtin_amdgcn_mfma_f32_16x16x16bf16_1k(p[st], ones, Osum, 0, 0, 0);
            }

            // ---- PV: O[dt] += P * V (B-frags from swizzled Vt) ----
#pragma unroll
            for (int dt = 0; dt < 4; ++dt) {
                const int d = dt * 16 + l15;
                const int dx = l15 & 7;
#pragma unroll
                for (int st = 0; st < 4; ++st) {
                    const int ch = (st * 2 + (quad >> 1)) ^ dx;
                    bf16x4 vb = *(const bf16x4*)&VtH[d * 64 + ch * 8 + (quad & 1) * 4];
                    O[dt] = __builtin_amdgcn_mfma_f32_16x16x16bf16_1k(p[st], vb, O[dt], 0, 0, 0);
                }
            }
        }
        __builtin_amdgcn_s_setprio(0);
        __syncthreads();   // readers done with buf(it); drains DMA(it+1) post-compute
    }

    // ---- epilogue: direct store, wave-local denominator ----
    float inv[4];
#pragma unroll
    for (int r = 0; r < 4; ++r) inv[r] = 1.0f / Osum[r];
#pragma unroll
    for (int r = 0; r < 4; ++r) {
        const int row = q0 + w * 16 + quad * 4 + r;
        unsigned short* dst = ctx + ((size_t)bh * SEQ + row) * DH + l15;
#pragma unroll
        for (int dt = 0; dt < 4; ++dt)
            dst[dt * 16] = f2bf(O[dt][r] * inv[r]);
    }
}

// ---------------------------------------------------------------------------
// Kernel 3: output projection via MFMA, DMA-staged + double-buffered.
// (frozen)
// ---------------------------------------------------------------------------
__global__ __launch_bounds__(256, 4) void outproj_mfma(
    const unsigned short* __restrict__ ctx, const unsigned short* __restrict__ Wob,
    const float* __restrict__ bo, float* __restrict__ out)
{
    const int n0 = blockIdx.x * 64;
    const int m0 = blockIdx.y * 64;
    const int b  = m0 / SEQ;
    const int s0 = m0 % SEQ;

    __shared__ unsigned char smem[32768];   // buf(16K) x2: [A 8K | W 8K]

    const int t    = threadIdx.x;
    const int w    = t >> 6;
    const int lane = t & 63;
    const int l15  = lane & 15;
    const int quad = lane >> 4;
    const int srow   = lane >> 3;
    const int schunk = (lane & 7) ^ srow;

    const unsigned short* abase = ctx + ((size_t)b * HEADS * SEQ + s0 + srow) * DH + schunk * 8;
    const unsigned short* wbase = Wob + (size_t)(n0 + srow) * EMBED + schunk * 8;

    f32x4 acc[4] = {f32x4{0,0,0,0}, f32x4{0,0,0,0}, f32x4{0,0,0,0}, f32x4{0,0,0,0}};

    {
        unsigned char* Ab = smem;
        unsigned char* Wb = smem + 8192;
#pragma unroll
        for (int j = 0; j < 4; ++j) {
            const int idx = w * 4 + j;
            if (idx < 8)
                gl_lds16(abase + (size_t)idx * 8 * DH, Ab + idx * 1024);
            else
                gl_lds16(wbase + (size_t)(idx - 8) * 8 * EMBED, Wb + (idx - 8) * 1024);
        }
    }
    __syncthreads();

    for (int kt = 0; kt < 16; ++kt) {
        if (kt < 15) {
            const int ktn = kt + 1;
            unsigned char* Ab = smem + (ktn & 1) * 16384;
            unsigned char* Wb = Ab + 8192;
#pragma unroll
            for (int j = 0; j < 4; ++j) {
                const int idx = w * 4 + j;
                if (idx < 8)
                    gl_lds16(abase + (size_t)ktn * SEQ * DH + (size_t)idx * 8 * DH,
                             Ab + idx * 1024);
                else
                    gl_lds16(wbase + (size_t)(idx - 8) * 8 * EMBED + ktn * 64,
                             Wb + (idx - 8) * 1024);
            }
        }

        const unsigned short* At = (const unsigned short*)(smem + (kt & 1) * 16384);
        const unsigned short* Wt = At + 4096;
        const int rx = l15 & 7;
        const int c0 = ((quad ^ rx)) * 8;

        bf16x8 bf0 = *(const bf16x8*)&Wt[(w * 16 + l15) * 64 + c0];
        bf16x8 bf1 = *(const bf16x8*)&Wt[(w * 16 + l15) * 64 + (c0 ^ 32)];
#pragma unroll
        for (int mt = 0; mt < 4; ++mt) {
            bf16x8 af0 = *(const bf16x8*)&At[(mt * 16 + l15) * 64 + c0];
            bf16x8 af1 = *(const bf16x8*)&At[(mt * 16 + l15) * 64 + (c0 ^ 32)];
            acc[mt] = __builtin_amdgcn_mfma_f32_16x16x32_bf16(af0, bf0, acc[mt], 0, 0, 0);
            acc[mt] = __builtin_amdgcn_mfma_f32_16x16x32_bf16(af1, bf1, acc[mt], 0, 0, 0);
        }
        __syncthreads();
    }

    const float bv = bo[n0 + w * 16 + l15];
#pragma unroll
    for (int mt = 0; mt < 4; ++mt) {
#pragma unroll
        for (int r = 0; r < 4; ++r) {
            out[(size_t)(m0 + mt * 16 + quad * 4 + r) * EMBED + n0 + w * 16 + l15] =
                acc[mt][r] + bv;
        }
    }
}

// ---------------------------------------------------------------------------
extern "C" void kernel_launch(void* const* d_in, const int* in_sizes, int n_in,
                              void* d_out, int out_size, void* d_ws, size_t ws_size,
                              hipStream_t stream) {
    const float* k    = (const float*)d_in[0];
    const float* q    = (const float*)d_in[1];
    const float* v    = (const float*)d_in[2];
    const int*   mask = (const int*)  d_in[3];
    const float* Wk   = (const float*)d_in[4];
    const float* bk   = (const float*)d_in[5];
    const float* Wq   = (const float*)d_in[6];
    const float* bq   = (const float*)d_in[7];
    const float* Wv   = (const float*)d_in[8];
    const float* bv   = (const float*)d_in[9];
    const float* Wo   = (const float*)d_in[10];
    const float* bo   = (const float*)d_in[11];
    float* out = (float*)d_out;

    const size_t TEN = (size_t)BATCH * HEADS * SEQ * DH;   // 4,194,304 elems
    unsigned short* qh_bf = (unsigned short*)d_ws;         // 8 MB
    unsigned short* kh_bf = qh_bf + TEN;                   // 8 MB
    unsigned short* vt_bf = kh_bf + TEN;                   // 8 MB
    unsigned short* ctxb  = vt_bf + TEN;                   // 8 MB
    unsigned short* Wob   = ctxb + TEN;                    // 2 MB
    u64*            mbits = (u64*)(Wob + EMBED * EMBED);   // 1 MB  (35 MB total)

    proj_mfma<<<dim3(1024, 4), 256, 0, stream>>>(
        q, k, v, Wq, bq, Wk, bk, Wv, bv,
        qh_bf, kh_bf, vt_bf, mask, mbits, Wo, Wob);
    attn_kernel<<<dim3((SEQ / 128) * BATCH * HEADS), 512, 0, stream>>>(
        qh_bf, kh_bf, vt_bf, mbits, ctxb);
    outproj_mfma<<<dim3(EMBED / 64, BATCH * SEQ / 64), 256, 0, stream>>>(
        ctxb, Wob, bo, out);
}